// Round 3
// baseline (134.880 us; speedup 1.0000x reference)
//
#include <hip/hip_runtime.h>

#define EPS 1e-3f
#define SLOPE 0.01f
#define TPW 4    // 16-point tiles per wave (K1)
#define TPWF 8   // tiles per wave (fused K2+final; grid must fit co-resident)
#define NBANK 16 // stats atomic spread banks

typedef __attribute__((ext_vector_type(8))) short s8v;
typedef __attribute__((ext_vector_type(4))) float f4v;

union U4S8 {
  uint4 u;
  s8v s;
};

static __device__ inline unsigned f2bf(float x) {  // RNE f32->bf16 (low 16)
  unsigned u = __float_as_uint(x);
  return (u + 0x7fffu + ((u >> 16) & 1u)) >> 16;
}
static __device__ inline float bf_lo(unsigned u) {
  return __uint_as_float(u << 16);
}
static __device__ inline float bf_hi(unsigned u) {
  return __uint_as_float(u & 0xffff0000u);
}

// ---------------------------------------------------------------------------
// prep kernel: fused {feature f32->bf16 convert | sums/zero-row/ctr init |
// K1 B-fragment table build}. One dispatch replaces three tiny ones.
// ---------------------------------------------------------------------------
__global__ __launch_bounds__(256) void prep_kernel(
    const float* __restrict__ features, uint4* __restrict__ fbf, int n8,
    const float* __restrict__ w1, const float* __restrict__ w2,
    uint4* __restrict__ tab, float* __restrict__ sums, uint4* __restrict__ r0,
    uint4* __restrict__ r1, uint4* __restrict__ r2, unsigned* __restrict__ ctr,
    int nc) {
  const int b = blockIdx.x;
  const int tid = threadIdx.x;
  if (b < nc) {  // cvt: features f32 -> bf16 rows
    int i = b * 256 + tid;
    if (i < n8) {
      const float4* p = (const float4*)features + (size_t)i * 2;
      float4 a = p[0], bb = p[1];
      uint4 o;
      o.x = f2bf(a.x) | (f2bf(a.y) << 16);
      o.y = f2bf(a.z) | (f2bf(a.w) << 16);
      o.z = f2bf(bb.x) | (f2bf(bb.y) << 16);
      o.w = f2bf(bb.z) | (f2bf(bb.w) << 16);
      fbf[i] = o;
    }
  } else if (b == nc) {  // init: stats accumulators + zero rows + sync ctr
#pragma unroll
    for (int i = 0; i < 16; i++) sums[i * 256 + tid] = 0.f;
    uint4 z = {0u, 0u, 0u, 0u};
    if (tid < 2) r0[tid] = z;
    else if (tid < 6) r1[tid - 2] = z;
    else if (tid < 10) r2[tid - 6] = z;
    else if (tid == 10) *ctr = 0u;
  } else if (tid < 64) {  // build K1 tables (20 slot-blocks)
    const int sb = b - nc - 1;  // 0..19
    const int conv = sb / 10, slot = sb % 10;
    const float* w = conv ? w2 : w1;
    const int T = slot >> 1, f = slot & 1;
    const int g = tid >> 4, c = tid & 15;
    s8v t;
#pragma unroll
    for (int j = 0; j < 8; j++) {
      int kl = g * 8 + j;
      int tap = 2 * T + (kl >> 4);
      int ci = kl & 15;
      t[j] = (short)(tap < 9 ? f2bf(w[(tap * 16 + ci) * 32 + 2 * c + f]) : 0);
    }
    U4S8 u;
    u.s = t;
    tab[(conv * 10 + slot) * 64 + tid] = u.u;
  }
}

__global__ __launch_bounds__(64) void build_tab_k2(
    const float* __restrict__ w12, const float* __restrict__ w3,
    const float* __restrict__ sums1, const float* __restrict__ sums2,
    const float* __restrict__ g0, const float* __restrict__ b0,
    const float* __restrict__ g1, const float* __restrict__ b1,
    uint4* __restrict__ tab, int n) {
  __shared__ float stl[64];
  const int conv = blockIdx.x / 20, slot = blockIdx.x % 20;
  const float* w = conv ? w3 : w12;
  const float* sums = conv ? sums2 : sums1;
  const float* bn_g = conv ? g1 : g0;
  const float* bn_b = conv ? b1 : b0;
  const int lane = threadIdx.x;
  if (lane < 32) {
    float ssum = 0.f, qsum = 0.f;
#pragma unroll
    for (int bk = 0; bk < NBANK; bk++) {  // reduce spread banks
      ssum += sums[bk * 64 + lane];
      qsum += sums[bk * 64 + 32 + lane];
    }
    float inv_n = 1.0f / (float)n;
    float m = ssum * inv_n;
    float v = qsum * inv_n - m * m;
    float s = bn_g[lane] * rsqrtf(v + EPS);
    stl[lane] = s;
    stl[32 + lane] = bn_b[lane] - m * s;
  }
  __syncthreads();
  const int g = lane >> 4, c = lane & 15;
  s8v t;
  if (slot < 18) {
    const int k = slot >> 1, f = slot & 1;
#pragma unroll
    for (int j = 0; j < 8; j++) {
      int ci = g * 8 + j;
      t[j] = (short)f2bf(w[(k * 32 + ci) * 32 + 2 * c + f] * stl[ci]);
    }
  } else {
    const int f = slot - 18;
#pragma unroll
    for (int j = 0; j < 8; j++) {
      int kk = g * 8 + j;
      if (kk < 9) {
        float a = 0.f;
        for (int ci = 0; ci < 32; ci++)
          a += stl[32 + ci] * w[(kk * 32 + ci) * 32 + 2 * c + f];
        t[j] = (short)f2bf(a);
      } else {
        t[j] = 0;
      }
    }
  }
  U4S8 u;
  u.s = t;
  tab[(conv * 20 + slot) * 64 + lane] = u.u;
}

// ---------------------------------------------------------------------------
// K1 MFMA subm-conv (paired variant): prebuilt tables, even/odd cout
// split, direct packed stores, zero-row gathers, NBANK-spread stats atomics.
// ---------------------------------------------------------------------------
template <bool PAIRED>
__global__ __launch_bounds__(256, 3) void conv_mfma(
    const unsigned short* __restrict__ src0, const int* __restrict__ nbr0,
    const uint4* __restrict__ tab0, unsigned short* __restrict__ dst0,
    float* __restrict__ osums0, const unsigned short* __restrict__ src1,
    const int* __restrict__ nbr1, const uint4* __restrict__ tab1,
    unsigned short* __restrict__ dst1, float* __restrict__ osums1, int n,
    int gb) {
  constexpr int NS = PAIRED ? 5 : 9;      // mfma slots per tile
  constexpr int NSLOT = PAIRED ? 10 : 20; // table slots
  __shared__ uint4 bwl[NSLOT * 64];
  __shared__ float redl[4 * 64];

  const int tid = threadIdx.x;
  const bool second = (int)blockIdx.x >= gb;
  const unsigned short* src = second ? src1 : src0;
  const int* nbr = second ? nbr1 : nbr0;
  const uint4* tab = second ? tab1 : tab0;
  unsigned short* dst = second ? dst1 : dst0;
  float* osums = second ? osums1 : osums0;

  // stage table global -> LDS (coalesced)
  for (int i = tid; i < NSLOT * 64; i += 256) bwl[i] = tab[i];
  __syncthreads();

  const int lane = tid & 63;
  const int wv = tid >> 6;
  const int g = lane >> 4;  // k-chunk group 0..3
  const int c = lane & 15;  // A row (point) / B col index (cout pair c)

  s8v bbias0, bbias1;
  if (!PAIRED) {
    U4S8 x;
    x.u = bwl[18 * 64 + lane];
    bbias0 = x.s;
    x.u = bwl[19 * 64 + lane];
    bbias1 = x.s;
  }

  const int bid = second ? (int)blockIdx.x - gb : (int)blockIdx.x;
  const int wbase = bid * (64 * TPW) + wv * (16 * TPW);

  float s0 = 0.f, s1 = 0.f, q0 = 0.f, q1 = 0.f;  // stats accumulators

  int jj[9], jjn[9];
  {
    int pt = wbase + c;
    bool a = pt < n;
#pragma unroll
    for (int k = 0; k < 9; k++) jj[k] = a ? nbr[(size_t)k * n + pt] : -1;
  }

#pragma unroll 1
  for (int t = 0; t < TPW; t++) {
    const int pbase = wbase + t * 16;
    {  // prefetch next tile's indices
      int pt = pbase + 16 + c;
      bool a = (t + 1 < TPW) && (pt < n);
#pragma unroll
      for (int k = 0; k < 9; k++) jjn[k] = a ? nbr[(size_t)k * n + pt] : -1;
    }
    unsigned vmask = 0;
    if (!PAIRED) {
#pragma unroll
      for (int k = 0; k < 9; k++) vmask |= (jj[k] >= 0 ? 1u : 0u) << k;
    }

    // ---- per-slot wave-uniform validity (ballot -> SGPR scalar branch) ----
    bool slot_on[NS];
#pragma unroll
    for (int s = 0; s < NS; s++) {
      if (PAIRED) {
        int jA = jj[2 * s];
        int jB = jj[(2 * s + 1 < 9) ? 2 * s + 1 : 8];
        slot_on[s] = __ballot(jA >= 0 || jB >= 0) != 0ull;
      } else {
        slot_on[s] = __ballot(jj[s] >= 0) != 0ull;
      }
    }

    // ---- issue gathers for live slots (all in flight before MFMAs) ----
    uint4 ga[NS];
#pragma unroll
    for (int s = 0; s < NS; s++) {
      if (slot_on[s]) {
        int jr;
        if (PAIRED) {
          int jA = jj[2 * s];
          int jB = jj[(2 * s + 1 < 9) ? 2 * s + 1 : 8];
          jr = (g & 2) ? jB : jA;
        } else {
          jr = jj[s];
        }
        unsigned jc = jr < 0 ? (unsigned)n : (unsigned)jr;  // zero row
        const uint4* p =
            (const uint4*)src +
            (PAIRED ? ((size_t)jc * 2 + (g & 1)) : ((size_t)jc * 4 + g));
        ga[s] = p[0];
      }
    }
    __builtin_amdgcn_sched_barrier(0);  // pin: loads above, MFMAs below

    // ---- MFMA accumulate (live slots only) ----
    f4v acc0 = {0.f, 0.f, 0.f, 0.f};
    f4v acc1 = {0.f, 0.f, 0.f, 0.f};
#pragma unroll
    for (int s = 0; s < NS; s++) {
      if (slot_on[s]) {
        U4S8 a;
        a.u = ga[s];
        U4S8 b0, b1;
        b0.u = bwl[(s * 2 + 0) * 64 + lane];
        b1.u = bwl[(s * 2 + 1) * 64 + lane];
        acc0 = __builtin_amdgcn_mfma_f32_16x16x32_bf16(a.s, b0.s, acc0, 0, 0, 0);
        acc1 = __builtin_amdgcn_mfma_f32_16x16x32_bf16(a.s, b1.s, acc1, 0, 0, 0);
      }
    }
    if (!PAIRED) {  // bias via validity-matrix MFMA (covers all taps)
      s8v av;
#pragma unroll
      for (int j = 0; j < 8; j++) {
        unsigned kk = (unsigned)(g * 8 + j);
        unsigned bit = (kk < 32u) ? ((vmask >> kk) & 1u) : 0u;
        av[j] = (short)(bit ? 0x3F80 : 0);
      }
      acc0 = __builtin_amdgcn_mfma_f32_16x16x32_bf16(av, bbias0, acc0, 0, 0, 0);
      acc1 = __builtin_amdgcn_mfma_f32_16x16x32_bf16(av, bbias1, acc1, 0, 0, 0);
    }

    // ---- lrelu + stats ----
#pragma unroll
    for (int r = 0; r < 4; r++) {
      float x = acc0[r];
      x = fmaxf(x, SLOPE * x);
      acc0[r] = x;
      s0 += x;
      q0 = fmaf(x, x, q0);
      float y = acc1[r];
      y = fmaxf(y, SLOPE * y);
      acc1[r] = y;
      s1 += y;
      q1 = fmaf(y, y, q1);
    }

    // ---- direct coalesced store: lane (g,c) owns points pbase+g*4+r,
    //      couts (2c,2c+1) -> one packed bf16x2 dword each ----
#pragma unroll
    for (int r = 0; r < 4; r++) {
      int p = pbase + g * 4 + r;
      if (p < n)
        ((unsigned*)dst)[(size_t)p * 16 + c] =
            f2bf(acc0[r]) | (f2bf(acc1[r]) << 16);
    }
#pragma unroll
    for (int k = 0; k < 9; k++) jj[k] = jjn[k];
  }

  // ---- block stats reduction, one atomic per channel into spread bank ----
  s0 += __shfl_xor(s0, 16, 64);
  s0 += __shfl_xor(s0, 32, 64);
  s1 += __shfl_xor(s1, 16, 64);
  s1 += __shfl_xor(s1, 32, 64);
  q0 += __shfl_xor(q0, 16, 64);
  q0 += __shfl_xor(q0, 32, 64);
  q1 += __shfl_xor(q1, 16, 64);
  q1 += __shfl_xor(q1, 32, 64);
  if (lane < 16) {
    redl[wv * 64 + 2 * c] = s0;
    redl[wv * 64 + 2 * c + 1] = s1;
    redl[wv * 64 + 32 + 2 * c] = q0;
    redl[wv * 64 + 32 + 2 * c + 1] = q1;
  }
  __syncthreads();
  if (tid < 64) {
    float t = redl[tid] + redl[64 + tid] + redl[128 + tid] + redl[192 + tid];
    atomicAdd(&osums[(bid & (NBANK - 1)) * 64 + tid], t);
  }
}

// ---------------------------------------------------------------------------
// R16: fused K2 + final, NORMAL launch (graph-capturable) + scoped-atomic
// grid handoff. R14/R15 failed with IDENTICAL outputs across two different
// sync schemes + poison-valued absmax in the timed phase => the cooperative
// launch was silently rejected under stream capture and the kernel NEVER RAN
// (pytest err == absmax(ref), a constant). Fix: plain <<<>>> launch; the
// atomic-counter handoff never needed cooperative semantics, only
// co-residency, which is guaranteed arithmetically: grid=489 <= 2 blk/CU
// (launch_bounds(256,2) => <=256 VGPR => 8 waves/CU; LDS 41.75KB => 3/CU)
// x 256 CU = 512 slots. All blocks resident from dispatch => spin terminates.
// ---------------------------------------------------------------------------
__global__ __launch_bounds__(256, 2) void conv_mfma_final(
    const unsigned short* __restrict__ srcA, const int* __restrict__ nbrA,
    const unsigned short* __restrict__ srcB, const int* __restrict__ nbrB,
    const uint4* __restrict__ tab, float* __restrict__ sumsA,
    float* __restrict__ sumsB, const float* __restrict__ gA,
    const float* __restrict__ bA, const float* __restrict__ gB,
    const float* __restrict__ bB, float* __restrict__ out,
    unsigned* __restrict__ ctr, int n) {
  __shared__ uint4 bwl[40 * 64];
  __shared__ float redl[4 * 64];
  __shared__ float st[128];

  const int tid = threadIdx.x;
  for (int i = tid; i < 40 * 64; i += 256) bwl[i] = tab[i];
  __syncthreads();

  const int lane = tid & 63;
  const int wv = tid >> 6;
  const int g = lane >> 4;
  const int c = lane & 15;
  const int bid = (int)blockIdx.x;
  const int wbase = bid * (64 * TPWF) + wv * (16 * TPWF);

  unsigned zheld[2][TPWF][4];  // packed bf16x2 per (conv, tile, row)

#pragma unroll
  for (int conv = 0; conv < 2; conv++) {
    const unsigned short* src = conv ? srcB : srcA;
    const int* nbr = conv ? nbrB : nbrA;
    float* osums = conv ? sumsB : sumsA;
    const int toff = conv * 20 * 64;

    s8v bbias0, bbias1;
    {
      U4S8 x;
      x.u = bwl[toff + 18 * 64 + lane];
      bbias0 = x.s;
      x.u = bwl[toff + 19 * 64 + lane];
      bbias1 = x.s;
    }

    float s0 = 0.f, s1 = 0.f, q0 = 0.f, q1 = 0.f;
    int jj[9], jjn[9];
    {
      int pt = wbase + c;
      bool a = pt < n;
#pragma unroll
      for (int k = 0; k < 9; k++) jj[k] = a ? nbr[(size_t)k * n + pt] : -1;
    }

#pragma unroll
    for (int t = 0; t < TPWF; t++) {  // FULL unroll: zheld static indexing
      const int pbase = wbase + t * 16;
      {
        int pt = pbase + 16 + c;
        bool a = (t + 1 < TPWF) && (pt < n);
#pragma unroll
        for (int k = 0; k < 9; k++)
          jjn[k] = a ? nbr[(size_t)k * n + pt] : -1;
      }
      unsigned vmask = 0;
#pragma unroll
      for (int k = 0; k < 9; k++) vmask |= (jj[k] >= 0 ? 1u : 0u) << k;

      bool slot_on[9];
#pragma unroll
      for (int s = 0; s < 9; s++) slot_on[s] = __ballot(jj[s] >= 0) != 0ull;

      uint4 ga[9];
#pragma unroll
      for (int s = 0; s < 9; s++) {
        if (slot_on[s]) {
          int jr = jj[s];
          unsigned jc = jr < 0 ? (unsigned)n : (unsigned)jr;  // zero row
          ga[s] = ((const uint4*)src)[(size_t)jc * 4 + g];
        }
      }
      __builtin_amdgcn_sched_barrier(0);  // pin: loads above, MFMAs below

      f4v acc0 = {0.f, 0.f, 0.f, 0.f};
      f4v acc1 = {0.f, 0.f, 0.f, 0.f};
#pragma unroll
      for (int s = 0; s < 9; s++) {
        if (slot_on[s]) {
          U4S8 a;
          a.u = ga[s];
          U4S8 b0, b1;
          b0.u = bwl[toff + (s * 2 + 0) * 64 + lane];
          b1.u = bwl[toff + (s * 2 + 1) * 64 + lane];
          acc0 =
              __builtin_amdgcn_mfma_f32_16x16x32_bf16(a.s, b0.s, acc0, 0, 0, 0);
          acc1 =
              __builtin_amdgcn_mfma_f32_16x16x32_bf16(a.s, b1.s, acc1, 0, 0, 0);
        }
      }
      {  // bias via validity-matrix MFMA (covers all taps)
        s8v av;
#pragma unroll
        for (int j = 0; j < 8; j++) {
          unsigned kk = (unsigned)(g * 8 + j);
          unsigned bit = (kk < 32u) ? ((vmask >> kk) & 1u) : 0u;
          av[j] = (short)(bit ? 0x3F80 : 0);
        }
        acc0 =
            __builtin_amdgcn_mfma_f32_16x16x32_bf16(av, bbias0, acc0, 0, 0, 0);
        acc1 =
            __builtin_amdgcn_mfma_f32_16x16x32_bf16(av, bbias1, acc1, 0, 0, 0);
      }

      // lrelu + stats + pack bf16 into held registers (no global store)
#pragma unroll
      for (int r = 0; r < 4; r++) {
        float x = acc0[r];
        x = fmaxf(x, SLOPE * x);
        s0 += x;
        q0 = fmaf(x, x, q0);
        float y = acc1[r];
        y = fmaxf(y, SLOPE * y);
        s1 += y;
        q1 = fmaf(y, y, q1);
        zheld[conv][t][r] = f2bf(x) | (f2bf(y) << 16);
      }
#pragma unroll
      for (int k = 0; k < 9; k++) jj[k] = jjn[k];
    }

    // block stats reduction, one atomic per channel into spread bank
    s0 += __shfl_xor(s0, 16, 64);
    s0 += __shfl_xor(s0, 32, 64);
    s1 += __shfl_xor(s1, 16, 64);
    s1 += __shfl_xor(s1, 32, 64);
    q0 += __shfl_xor(q0, 16, 64);
    q0 += __shfl_xor(q0, 32, 64);
    q1 += __shfl_xor(q1, 16, 64);
    q1 += __shfl_xor(q1, 32, 64);
    __syncthreads();  // protect redl reuse between convs
    if (lane < 16) {
      redl[wv * 64 + 2 * c] = s0;
      redl[wv * 64 + 2 * c + 1] = s1;
      redl[wv * 64 + 32 + 2 * c] = q0;
      redl[wv * 64 + 32 + 2 * c + 1] = q1;
    }
    __syncthreads();
    if (tid < 64) {
      float t = redl[tid] + redl[64 + tid] + redl[128 + tid] + redl[192 + tid];
      atomicAdd(&osums[(bid & (NBANK - 1)) * 64 + tid], t);
    }
  }

  // ---- explicit grid handoff: release our atomics, wait for all blocks ----
  __syncthreads();  // all block threads' atomicAdds happen-before tid0's release
  if (tid == 0) {
    __hip_atomic_fetch_add(ctr, 1u, __ATOMIC_ACQ_REL, __HIP_MEMORY_SCOPE_AGENT);
    while (__hip_atomic_load(ctr, __ATOMIC_ACQUIRE, __HIP_MEMORY_SCOPE_AGENT) <
           gridDim.x)
      __builtin_amdgcn_s_sleep(2);
  }
  __syncthreads();  // tid0's acquire happens-before all block threads' reads

  if (tid < 32) {
    float sa = 0.f, qa = 0.f, sb = 0.f, qb = 0.f;
#pragma unroll
    for (int bk = 0; bk < NBANK; bk++) {  // agent-scope atomic loads: fresh
      sa += __hip_atomic_load(&sumsA[bk * 64 + tid], __ATOMIC_RELAXED,
                              __HIP_MEMORY_SCOPE_AGENT);
      qa += __hip_atomic_load(&sumsA[bk * 64 + 32 + tid], __ATOMIC_RELAXED,
                              __HIP_MEMORY_SCOPE_AGENT);
      sb += __hip_atomic_load(&sumsB[bk * 64 + tid], __ATOMIC_RELAXED,
                              __HIP_MEMORY_SCOPE_AGENT);
      qb += __hip_atomic_load(&sumsB[bk * 64 + 32 + tid], __ATOMIC_RELAXED,
                              __HIP_MEMORY_SCOPE_AGENT);
    }
    float inv_n = 1.0f / (float)n;
    float m = sa * inv_n;
    float v = qa * inv_n - m * m;
    float s = gA[tid] * rsqrtf(v + EPS);
    st[tid] = s;
    st[32 + tid] = bA[tid] - m * s;
    m = sb * inv_n;
    v = qb * inv_n - m * m;
    s = gB[tid] * rsqrtf(v + EPS);
    st[64 + tid] = s;
    st[96 + tid] = bB[tid] - m * s;
  }
  __syncthreads();

  const int c2 = 2 * c;
  const float sA0 = st[c2], tA0 = st[32 + c2];
  const float sB0 = st[64 + c2], tB0 = st[96 + c2];
  const float sA1 = st[c2 + 1], tA1 = st[32 + c2 + 1];
  const float sB1 = st[64 + c2 + 1], tB1 = st[96 + c2 + 1];
#pragma unroll
  for (int t = 0; t < TPWF; t++) {
    const int pbase = wbase + t * 16;
#pragma unroll
    for (int r = 0; r < 4; r++) {
      int p = pbase + g * 4 + r;
      if (p < n) {
        unsigned za = zheld[0][t][r], zb = zheld[1][t][r];
        float2 o;
        o.x = bf_lo(za) * sA0 + tA0 + bf_lo(zb) * sB0 + tB0;
        o.y = bf_hi(za) * sA1 + tA1 + bf_hi(zb) * sB1 + tB1;
        ((float2*)out)[(size_t)p * 16 + c] = o;
      }
    }
  }
}

extern "C" void kernel_launch(void* const* d_in, const int* in_sizes, int n_in,
                              void* d_out, int out_size, void* d_ws,
                              size_t ws_size, hipStream_t stream) {
  const float* features = (const float*)d_in[0];
  const int* nbr133 = (const int*)d_in[1];
  const int* nbr313 = (const int*)d_in[2];
  const float* conv1_w = (const float*)d_in[3];
  const float* conv12_w = (const float*)d_in[4];
  const float* conv2_w = (const float*)d_in[5];
  const float* conv3_w = (const float*)d_in[6];
  const float* bn0_g = (const float*)d_in[7];
  const float* bn0_b = (const float*)d_in[8];
  const float* bn02_g = (const float*)d_in[9];
  const float* bn02_b = (const float*)d_in[10];
  const float* bn1_g = (const float*)d_in[11];
  const float* bn1_b = (const float*)d_in[12];
  const float* bn2_g = (const float*)d_in[13];
  const float* bn2_b = (const float*)d_in[14];
  float* out = (float*)d_out;

  const int n = in_sizes[0] / 16;  // 250000
  char* ws = (char*)d_ws;
  const size_t A = (size_t)n * 64 + 64;  // bf16 [n+1][32] region

  // region0: fbf ([n+1][16] bf16); zA1/zA2 are K1 outputs ([n+1][32] bf16)
  unsigned short* fbf = (unsigned short*)ws;
  unsigned short* zA1 = (unsigned short*)(ws + A);
  unsigned short* zA2 = (unsigned short*)(ws + 2 * A);
  float* sums = (float*)(ws + 4 * A);
  // sums: 4 stat sets x NBANK banks x 64 floats:
  //   +0 z1 | +1024 z2 | +2048 z12 | +3072 z3
  uint4* tabK1 = (uint4*)(ws + 4 * A + 4 * NBANK * 64 * 4);
  uint4* tabK2 = tabK1 + 20 * 64;
  unsigned* ctr = (unsigned*)(tabK2 + 40 * 64);

  const int n8 = n * 2;  // 8-float chunks of features
  const int nc = (n8 + 255) / 256;
  // fused prep: cvt | init | tabK1 build
  prep_kernel<<<nc + 21, 256, 0, stream>>>(
      features, (uint4*)fbf, n8, conv1_w, conv2_w, tabK1, sums,
      (uint4*)(ws + (size_t)n * 32),            // fbf row n
      (uint4*)(ws + A + (size_t)n * 64),        // zA1 row n
      (uint4*)(ws + 2 * A + (size_t)n * 64),    // zA2 row n
      ctr, nc);

  const int gb = (n + 64 * TPW - 1) / (64 * TPW);
  // K1: conv1 (fbf,nbr133)->zA1 || conv2 (fbf,nbr313)->zA2
  conv_mfma<true><<<2 * gb, 256, 0, stream>>>(
      fbf, nbr133, tabK1, zA1, sums + 0, fbf, nbr313, tabK1 + 10 * 64, zA2,
      sums + 1024, n, gb);
  // tables for K2 (BN of K1 folded in; needs K1 stats)
  build_tab_k2<<<40, 64, 0, stream>>>(conv12_w, conv3_w, sums + 0, sums + 1024,
                                      bn0_g, bn0_b, bn1_g, bn1_b, tabK2, n);
  // fused K2+final, NORMAL launch: conv12 (bn0(zA1),nbr313) + conv3
  // (bn1(zA2),nbr133), atomic grid handoff, out = bn02+bn2. 489 blocks
  // co-resident by construction (see kernel comment).
  const int gb2 = (n + 64 * TPWF - 1) / (64 * TPWF);
  conv_mfma_final<<<gb2, 256, 0, stream>>>(
      zA1, nbr313, zA2, nbr133, tabK2, sums + 2048, sums + 3072, bn02_g,
      bn02_b, bn2_g, bn2_b, out, ctr, n);
}

// Round 4
// 76.870 us; speedup vs baseline: 1.7546x; 1.7546x over previous
//
#include <hip/hip_runtime.h>

#define EPS 1e-3f
#define SLOPE 0.01f
#define TPW 4   // 16-point tiles per wave
#define NBANK 16  // stats atomic spread banks

typedef __attribute__((ext_vector_type(8))) short s8v;
typedef __attribute__((ext_vector_type(4))) float f4v;

union U4S8 {
  uint4 u;
  s8v s;
};

static __device__ inline unsigned f2bf(float x) {  // RNE f32->bf16 (low 16)
  unsigned u = __float_as_uint(x);
  return (u + 0x7fffu + ((u >> 16) & 1u)) >> 16;
}
static __device__ inline float bf_lo(unsigned u) {
  return __uint_as_float(u << 16);
}
static __device__ inline float bf_hi(unsigned u) {
  return __uint_as_float(u & 0xffff0000u);
}

// ---------------------------------------------------------------------------
// prep kernel: fused {feature f32->bf16 convert | sums/zero-row init |
// K1 B-fragment table build}. One dispatch replaces three tiny ones.
// ---------------------------------------------------------------------------
__global__ __launch_bounds__(256) void prep_kernel(
    const float* __restrict__ features, uint4* __restrict__ fbf, int n8,
    const float* __restrict__ w1, const float* __restrict__ w2,
    uint4* __restrict__ tab, float* __restrict__ sums, uint4* __restrict__ r0,
    uint4* __restrict__ r1, uint4* __restrict__ r2, int nc) {
  const int b = blockIdx.x;
  const int tid = threadIdx.x;
  if (b < nc) {  // cvt: features f32 -> bf16 rows
    int i = b * 256 + tid;
    if (i < n8) {
      const float4* p = (const float4*)features + (size_t)i * 2;
      float4 a = p[0], bb = p[1];
      uint4 o;
      o.x = f2bf(a.x) | (f2bf(a.y) << 16);
      o.y = f2bf(a.z) | (f2bf(a.w) << 16);
      o.z = f2bf(bb.x) | (f2bf(bb.y) << 16);
      o.w = f2bf(bb.z) | (f2bf(bb.w) << 16);
      fbf[i] = o;
    }
  } else if (b == nc) {  // init: stats accumulators + zero rows
#pragma unroll
    for (int i = 0; i < 16; i++) sums[i * 256 + tid] = 0.f;
    uint4 z = {0u, 0u, 0u, 0u};
    if (tid < 2) r0[tid] = z;
    else if (tid < 6) r1[tid - 2] = z;
    else if (tid < 10) r2[tid - 6] = z;
  } else if (tid < 64) {  // build K1 tables (20 slot-blocks)
    const int sb = b - nc - 1;  // 0..19
    const int conv = sb / 10, slot = sb % 10;
    const float* w = conv ? w2 : w1;
    const int T = slot >> 1, f = slot & 1;
    const int g = tid >> 4, c = tid & 15;
    s8v t;
#pragma unroll
    for (int j = 0; j < 8; j++) {
      int kl = g * 8 + j;
      int tap = 2 * T + (kl >> 4);
      int ci = kl & 15;
      t[j] = (short)(tap < 9 ? f2bf(w[(tap * 16 + ci) * 32 + 2 * c + f]) : 0);
    }
    U4S8 u;
    u.s = t;
    tab[(conv * 10 + slot) * 64 + tid] = u.u;
  }
}

__global__ __launch_bounds__(64) void build_tab_k2(
    const float* __restrict__ w12, const float* __restrict__ w3,
    const float* __restrict__ sums1, const float* __restrict__ sums2,
    const float* __restrict__ g0, const float* __restrict__ b0,
    const float* __restrict__ g1, const float* __restrict__ b1,
    uint4* __restrict__ tab, int n) {
  __shared__ float stl[64];
  const int conv = blockIdx.x / 20, slot = blockIdx.x % 20;
  const float* w = conv ? w3 : w12;
  const float* sums = conv ? sums2 : sums1;
  const float* bn_g = conv ? g1 : g0;
  const float* bn_b = conv ? b1 : b0;
  const int lane = threadIdx.x;
  if (lane < 32) {
    float ssum = 0.f, qsum = 0.f;
#pragma unroll
    for (int bk = 0; bk < NBANK; bk++) {  // reduce spread banks
      ssum += sums[bk * 64 + lane];
      qsum += sums[bk * 64 + 32 + lane];
    }
    float inv_n = 1.0f / (float)n;
    float m = ssum * inv_n;
    float v = qsum * inv_n - m * m;
    float s = bn_g[lane] * rsqrtf(v + EPS);
    stl[lane] = s;
    stl[32 + lane] = bn_b[lane] - m * s;
  }
  __syncthreads();
  const int g = lane >> 4, c = lane & 15;
  s8v t;
  if (slot < 18) {
    const int k = slot >> 1, f = slot & 1;
#pragma unroll
    for (int j = 0; j < 8; j++) {
      int ci = g * 8 + j;
      t[j] = (short)f2bf(w[(k * 32 + ci) * 32 + 2 * c + f] * stl[ci]);
    }
  } else {
    const int f = slot - 18;
#pragma unroll
    for (int j = 0; j < 8; j++) {
      int kk = g * 8 + j;
      if (kk < 9) {
        float a = 0.f;
        for (int ci = 0; ci < 32; ci++)
          a += stl[32 + ci] * w[(kk * 32 + ci) * 32 + 2 * c + f];
        t[j] = (short)f2bf(a);
      } else {
        t[j] = 0;
      }
    }
  }
  U4S8 u;
  u.s = t;
  tab[(conv * 20 + slot) * 64 + lane] = u.u;
}

// ---------------------------------------------------------------------------
// Pipeline helpers (forceinline; array refs resolve to caller registers).
// ---------------------------------------------------------------------------
__device__ __forceinline__ void load_idx(const int* __restrict__ nbr, int n,
                                         int pt, int (&JJ)[9]) {
  bool a = pt < n;
#pragma unroll
  for (int k = 0; k < 9; k++) JJ[k] = a ? nbr[(size_t)k * n + pt] : -1;
}

template <bool PAIRED, int NS>
__device__ __forceinline__ void produce(const unsigned short* __restrict__ src,
                                        int n, int g, const int (&JJ)[9],
                                        uint4 (&GA)[NS], unsigned& VM,
                                        unsigned& SON) {
  VM = 0;
#pragma unroll
  for (int k = 0; k < 9; k++) VM |= (JJ[k] >= 0 ? 1u : 0u) << k;
  SON = 0;
#pragma unroll
  for (int s = 0; s < NS; s++) {
    bool on;
    if (PAIRED) {
      int jA = JJ[2 * s];
      int jB = JJ[(2 * s + 1 < 9) ? 2 * s + 1 : 8];
      on = __ballot(jA >= 0 || jB >= 0) != 0ull;
    } else {
      on = __ballot(JJ[s] >= 0) != 0ull;
    }
    SON |= (on ? 1u : 0u) << s;
  }
#pragma unroll
  for (int s = 0; s < NS; s++) {
    if (SON & (1u << s)) {  // wave-uniform scalar branch
      int jr;
      if (PAIRED) {
        int jA = JJ[2 * s];
        int jB = JJ[(2 * s + 1 < 9) ? 2 * s + 1 : 8];
        jr = (g & 2) ? jB : jA;
      } else {
        jr = JJ[s];
      }
      unsigned jc = jr < 0 ? (unsigned)n : (unsigned)jr;  // zero row
      GA[s] = ((const uint4*)src)[PAIRED ? ((size_t)jc * 2 + (g & 1))
                                         : ((size_t)jc * 4 + g)];
    }
  }
}

// ---------------------------------------------------------------------------
// MFMA subm-conv, R17: 2-deep gather software pipeline. R16's counters showed
// the conv phase is pure gather-latency (MfmaUtil 2.6%, VALUBusy 9.4%, HBM
// 8.7%): gathers were issued and consumed within the same tile, so every
// tile eats a full ~600-900cy L3/HBM latency with only 3 waves/SIMD to
// overlap. Now: indices prefetched 2 tiles ahead (jjb ping-pong), gathers
// issued 1 tile ahead (gab ping-pong); MFMAs consume data gathered a full
// tile earlier. Fully unrolled t-loop => all buffer indices static (rule
// #20). K1 (PAIRED) at 4 blk/CU (est ~110 VGPR < 128 cap); K2 at 3 (~145 <
// 168 cap).
// ---------------------------------------------------------------------------
template <bool PAIRED, int MINB>
__global__ __launch_bounds__(256, MINB) void conv_mfma(
    const unsigned short* __restrict__ src0, const int* __restrict__ nbr0,
    const uint4* __restrict__ tab0, unsigned short* __restrict__ dst0,
    float* __restrict__ osums0, const unsigned short* __restrict__ src1,
    const int* __restrict__ nbr1, const uint4* __restrict__ tab1,
    unsigned short* __restrict__ dst1, float* __restrict__ osums1, int n,
    int gb) {
  constexpr int NS = PAIRED ? 5 : 9;      // mfma slots per tile
  constexpr int NSLOT = PAIRED ? 10 : 20; // table slots
  __shared__ uint4 bwl[NSLOT * 64];
  __shared__ float redl[4 * 64];

  const int tid = threadIdx.x;
  const bool second = (int)blockIdx.x >= gb;
  const unsigned short* src = second ? src1 : src0;
  const int* nbr = second ? nbr1 : nbr0;
  const uint4* tab = second ? tab1 : tab0;
  unsigned short* dst = second ? dst1 : dst0;
  float* osums = second ? osums1 : osums0;

  // stage table global -> LDS (coalesced)
  for (int i = tid; i < NSLOT * 64; i += 256) bwl[i] = tab[i];
  __syncthreads();

  const int lane = tid & 63;
  const int wv = tid >> 6;
  const int g = lane >> 4;  // k-chunk group 0..3
  const int c = lane & 15;  // A row (point) / B col index (cout pair c)

  s8v bbias0, bbias1;
  if (!PAIRED) {
    U4S8 x;
    x.u = bwl[18 * 64 + lane];
    bbias0 = x.s;
    x.u = bwl[19 * 64 + lane];
    bbias1 = x.s;
  }

  const int bid = second ? (int)blockIdx.x - gb : (int)blockIdx.x;
  const int wbase = bid * (64 * TPW) + wv * (16 * TPW);

  float s0 = 0.f, s1 = 0.f, q0 = 0.f, q1 = 0.f;  // stats accumulators

  // ---- software pipeline state: idx 2 tiles ahead, gathers 1 tile ahead ----
  int jjb[2][9];
  uint4 gab[2][NS];
  unsigned vmb[2], sonb[2];

  load_idx(nbr, n, wbase + c, jjb[0]);        // tile 0 indices
  load_idx(nbr, n, wbase + 16 + c, jjb[1]);   // tile 1 indices
  produce<PAIRED, NS>(src, n, g, jjb[0], gab[0], vmb[0], sonb[0]);  // tile 0

#pragma unroll
  for (int t = 0; t < TPW; t++) {  // FULL unroll: static ping-pong indices
    const int cur = t & 1, nxt = 1 - (t & 1);
    const int pbase = wbase + t * 16;

    if (t + 2 < TPW)  // issue indices for tile t+2 (into freed buffer)
      load_idx(nbr, n, pbase + 32 + c, jjb[cur]);
    if (t + 1 < TPW)  // issue gathers for tile t+1 (indices from iter t-1)
      produce<PAIRED, NS>(src, n, g, jjb[nxt], gab[nxt], vmb[nxt], sonb[nxt]);
    __builtin_amdgcn_sched_barrier(0);  // pin: loads above, MFMAs below

    // ---- MFMA accumulate tile t (data gathered one tile ago) ----
    f4v acc0 = {0.f, 0.f, 0.f, 0.f};
    f4v acc1 = {0.f, 0.f, 0.f, 0.f};
#pragma unroll
    for (int s = 0; s < NS; s++) {
      if (sonb[cur] & (1u << s)) {  // wave-uniform scalar branch
        U4S8 a;
        a.u = gab[cur][s];
        U4S8 b0, b1;
        b0.u = bwl[(s * 2 + 0) * 64 + lane];
        b1.u = bwl[(s * 2 + 1) * 64 + lane];
        acc0 = __builtin_amdgcn_mfma_f32_16x16x32_bf16(a.s, b0.s, acc0, 0, 0, 0);
        acc1 = __builtin_amdgcn_mfma_f32_16x16x32_bf16(a.s, b1.s, acc1, 0, 0, 0);
      }
    }
    if (!PAIRED) {  // bias via validity-matrix MFMA (covers all taps)
      unsigned vmask = vmb[cur];
      s8v av;
#pragma unroll
      for (int j = 0; j < 8; j++) {
        unsigned kk = (unsigned)(g * 8 + j);
        unsigned bit = (kk < 32u) ? ((vmask >> kk) & 1u) : 0u;
        av[j] = (short)(bit ? 0x3F80 : 0);
      }
      acc0 = __builtin_amdgcn_mfma_f32_16x16x32_bf16(av, bbias0, acc0, 0, 0, 0);
      acc1 = __builtin_amdgcn_mfma_f32_16x16x32_bf16(av, bbias1, acc1, 0, 0, 0);
    }

    // ---- lrelu + stats ----
#pragma unroll
    for (int r = 0; r < 4; r++) {
      float x = acc0[r];
      x = fmaxf(x, SLOPE * x);
      acc0[r] = x;
      s0 += x;
      q0 = fmaf(x, x, q0);
      float y = acc1[r];
      y = fmaxf(y, SLOPE * y);
      acc1[r] = y;
      s1 += y;
      q1 = fmaf(y, y, q1);
    }

    // ---- direct coalesced store: lane (g,c) owns points pbase+g*4+r,
    //      couts (2c,2c+1) -> one packed bf16x2 dword each ----
#pragma unroll
    for (int r = 0; r < 4; r++) {
      int p = pbase + g * 4 + r;
      if (p < n)
        ((unsigned*)dst)[(size_t)p * 16 + c] =
            f2bf(acc0[r]) | (f2bf(acc1[r]) << 16);
    }
  }

  // ---- block stats reduction, one atomic per channel into spread bank ----
  s0 += __shfl_xor(s0, 16, 64);
  s0 += __shfl_xor(s0, 32, 64);
  s1 += __shfl_xor(s1, 16, 64);
  s1 += __shfl_xor(s1, 32, 64);
  q0 += __shfl_xor(q0, 16, 64);
  q0 += __shfl_xor(q0, 32, 64);
  q1 += __shfl_xor(q1, 16, 64);
  q1 += __shfl_xor(q1, 32, 64);
  if (lane < 16) {
    redl[wv * 64 + 2 * c] = s0;
    redl[wv * 64 + 2 * c + 1] = s1;
    redl[wv * 64 + 32 + 2 * c] = q0;
    redl[wv * 64 + 32 + 2 * c + 1] = q1;
  }
  __syncthreads();
  if (tid < 64) {
    float t = redl[tid] + redl[64 + tid] + redl[128 + tid] + redl[192 + tid];
    atomicAdd(&osums[(bid & (NBANK - 1)) * 64 + tid], t);
  }
}

// out = bnA(z12) + bnB(z3), both inputs bf16 [n][32]; sums are NBANK-spread
__global__ __launch_bounds__(256) void final_kernel(
    const uint4* __restrict__ z12, const uint4* __restrict__ z3,
    float* __restrict__ out, const float* __restrict__ sumsA,
    const float* __restrict__ gA, const float* __restrict__ bA,
    const float* __restrict__ sumsB, const float* __restrict__ gB,
    const float* __restrict__ bB, int n) {
  __shared__ float st[128];  // sA tA sB tB
  const int tid = threadIdx.x;
  if (tid < 32) {
    float sa = 0.f, qa = 0.f, sb = 0.f, qb = 0.f;
#pragma unroll
    for (int bk = 0; bk < NBANK; bk++) {
      sa += sumsA[bk * 64 + tid];
      qa += sumsA[bk * 64 + 32 + tid];
      sb += sumsB[bk * 64 + tid];
      qb += sumsB[bk * 64 + 32 + tid];
    }
    float inv_n = 1.0f / (float)n;
    float m = sa * inv_n;
    float v = qa * inv_n - m * m;
    float s = gA[tid] * rsqrtf(v + EPS);
    st[tid] = s;
    st[32 + tid] = bA[tid] - m * s;
    m = sb * inv_n;
    v = qb * inv_n - m * m;
    s = gB[tid] * rsqrtf(v + EPS);
    st[64 + tid] = s;
    st[96 + tid] = bB[tid] - m * s;
  }
  __syncthreads();
  const int total = n * 4;  // 8-channel chunks
  for (int i = blockIdx.x * 256 + tid; i < total; i += gridDim.x * 256) {
    int c0 = (i & 3) * 8;
    uint4 a = z12[i], b = z3[i];
    float4 r0, r1;
    r0.x = bf_lo(a.x) * st[c0 + 0] + st[32 + c0 + 0] + bf_lo(b.x) * st[64 + c0 + 0] + st[96 + c0 + 0];
    r0.y = bf_hi(a.x) * st[c0 + 1] + st[32 + c0 + 1] + bf_hi(b.x) * st[64 + c0 + 1] + st[96 + c0 + 1];
    r0.z = bf_lo(a.y) * st[c0 + 2] + st[32 + c0 + 2] + bf_lo(b.y) * st[64 + c0 + 2] + st[96 + c0 + 2];
    r0.w = bf_hi(a.y) * st[c0 + 3] + st[32 + c0 + 3] + bf_hi(b.y) * st[64 + c0 + 3] + st[96 + c0 + 3];
    r1.x = bf_lo(a.z) * st[c0 + 4] + st[32 + c0 + 4] + bf_lo(b.z) * st[64 + c0 + 4] + st[96 + c0 + 4];
    r1.y = bf_hi(a.z) * st[c0 + 5] + st[32 + c0 + 5] + bf_hi(b.z) * st[64 + c0 + 5] + st[96 + c0 + 5];
    r1.z = bf_lo(a.w) * st[c0 + 6] + st[32 + c0 + 6] + bf_lo(b.w) * st[64 + c0 + 6] + st[96 + c0 + 6];
    r1.w = bf_hi(a.w) * st[c0 + 7] + st[32 + c0 + 7] + bf_hi(b.w) * st[64 + c0 + 7] + st[96 + c0 + 7];
    ((float4*)out)[2 * i + 0] = r0;
    ((float4*)out)[2 * i + 1] = r1;
  }
}

extern "C" void kernel_launch(void* const* d_in, const int* in_sizes, int n_in,
                              void* d_out, int out_size, void* d_ws,
                              size_t ws_size, hipStream_t stream) {
  const float* features = (const float*)d_in[0];
  const int* nbr133 = (const int*)d_in[1];
  const int* nbr313 = (const int*)d_in[2];
  const float* conv1_w = (const float*)d_in[3];
  const float* conv12_w = (const float*)d_in[4];
  const float* conv2_w = (const float*)d_in[5];
  const float* conv3_w = (const float*)d_in[6];
  const float* bn0_g = (const float*)d_in[7];
  const float* bn0_b = (const float*)d_in[8];
  const float* bn02_g = (const float*)d_in[9];
  const float* bn02_b = (const float*)d_in[10];
  const float* bn1_g = (const float*)d_in[11];
  const float* bn1_b = (const float*)d_in[12];
  const float* bn2_g = (const float*)d_in[13];
  const float* bn2_b = (const float*)d_in[14];
  float* out = (float*)d_out;

  const int n = in_sizes[0] / 16;  // 250000
  char* ws = (char*)d_ws;
  const size_t A = (size_t)n * 64 + 64;  // bf16 [n+1][32] region

  // region0: fbf ([n+1][16] bf16) overlaid later by z12 ([n][32] bf16)
  unsigned short* fbf = (unsigned short*)ws;
  unsigned short* z12 = (unsigned short*)ws;
  unsigned short* zA1 = (unsigned short*)(ws + A);
  unsigned short* zA2 = (unsigned short*)(ws + 2 * A);
  unsigned short* z3 = (unsigned short*)(ws + 3 * A);
  float* sums = (float*)(ws + 4 * A);
  // sums: 4 stat sets x NBANK banks x 64 floats:
  //   +0 z1 | +1024 z2 | +2048 z12 | +3072 z3
  uint4* tabK1 = (uint4*)(ws + 4 * A + 4 * NBANK * 64 * 4);
  uint4* tabK2 = tabK1 + 20 * 64;

  const int n8 = n * 2;  // 8-float chunks of features
  const int nc = (n8 + 255) / 256;
  // fused prep: cvt | init | tabK1 build
  prep_kernel<<<nc + 21, 256, 0, stream>>>(
      features, (uint4*)fbf, n8, conv1_w, conv2_w, tabK1, sums,
      (uint4*)(ws + (size_t)n * 32),            // fbf row n
      (uint4*)(ws + A + (size_t)n * 64),        // zA1 row n
      (uint4*)(ws + 2 * A + (size_t)n * 64),    // zA2 row n
      nc);

  const int gb = (n + 64 * TPW - 1) / (64 * TPW);
  // K1: conv1 (fbf,nbr133)->zA1 || conv2 (fbf,nbr313)->zA2
  conv_mfma<true, 4><<<2 * gb, 256, 0, stream>>>(
      fbf, nbr133, tabK1, zA1, sums + 0, fbf, nbr313, tabK1 + 10 * 64, zA2,
      sums + 1024, n, gb);
  // tables for K2 (BN of K1 folded in; needs K1 stats)
  build_tab_k2<<<40, 64, 0, stream>>>(conv12_w, conv3_w, sums + 0, sums + 1024,
                                      bn0_g, bn0_b, bn1_g, bn1_b, tabK2, n);
  // K2: conv12 (bn0(zA1),nbr313)->z12 || conv3 (bn1(zA2),nbr133)->z3
  conv_mfma<false, 3><<<2 * gb, 256, 0, stream>>>(
      zA1, nbr313, tabK2, z12, sums + 2048, zA2, nbr133, tabK2 + 20 * 64, z3,
      sums + 3072, n, gb);
  // out = bn02(z12) + bn2(z3)
  final_kernel<<<1024, 256, 0, stream>>>((const uint4*)z12, (const uint4*)z3,
                                         out, sums + 2048, bn02_g, bn02_b,
                                         sums + 3072, bn2_g, bn2_b, n);
}

// Round 5
// 75.287 us; speedup vs baseline: 1.7915x; 1.0210x over previous
//
#include <hip/hip_runtime.h>

#define EPS 1e-3f
#define SLOPE 0.01f
#define TPW 4   // 16-point tiles per wave
#define NBANK 16  // stats atomic spread banks

typedef __attribute__((ext_vector_type(8))) short s8v;
typedef __attribute__((ext_vector_type(4))) float f4v;

union U4S8 {
  uint4 u;
  s8v s;
};

static __device__ inline unsigned f2bf(float x) {  // RNE f32->bf16 (low 16)
  unsigned u = __float_as_uint(x);
  return (u + 0x7fffu + ((u >> 16) & 1u)) >> 16;
}
static __device__ inline float bf_lo(unsigned u) {
  return __uint_as_float(u << 16);
}
static __device__ inline float bf_hi(unsigned u) {
  return __uint_as_float(u & 0xffff0000u);
}

// ---------------------------------------------------------------------------
// prep kernel: fused {feature f32->bf16 convert | sums/zero-row init |
// K1 B-fragment table build}. One dispatch replaces three tiny ones.
// ---------------------------------------------------------------------------
__global__ __launch_bounds__(256) void prep_kernel(
    const float* __restrict__ features, uint4* __restrict__ fbf, int n8,
    const float* __restrict__ w1, const float* __restrict__ w2,
    uint4* __restrict__ tab, float* __restrict__ sums, uint4* __restrict__ r0,
    uint4* __restrict__ r1, uint4* __restrict__ r2, int nc) {
  const int b = blockIdx.x;
  const int tid = threadIdx.x;
  if (b < nc) {  // cvt: features f32 -> bf16 rows
    int i = b * 256 + tid;
    if (i < n8) {
      const float4* p = (const float4*)features + (size_t)i * 2;
      float4 a = p[0], bb = p[1];
      uint4 o;
      o.x = f2bf(a.x) | (f2bf(a.y) << 16);
      o.y = f2bf(a.z) | (f2bf(a.w) << 16);
      o.z = f2bf(bb.x) | (f2bf(bb.y) << 16);
      o.w = f2bf(bb.z) | (f2bf(bb.w) << 16);
      fbf[i] = o;
    }
  } else if (b == nc) {  // init: stats accumulators + zero rows
#pragma unroll
    for (int i = 0; i < 16; i++) sums[i * 256 + tid] = 0.f;
    uint4 z = {0u, 0u, 0u, 0u};
    if (tid < 2) r0[tid] = z;
    else if (tid < 6) r1[tid - 2] = z;
    else if (tid < 10) r2[tid - 6] = z;
  } else if (tid < 64) {  // build K1 tables (20 slot-blocks)
    const int sb = b - nc - 1;  // 0..19
    const int conv = sb / 10, slot = sb % 10;
    const float* w = conv ? w2 : w1;
    const int T = slot >> 1, f = slot & 1;
    const int g = tid >> 4, c = tid & 15;
    s8v t;
#pragma unroll
    for (int j = 0; j < 8; j++) {
      int kl = g * 8 + j;
      int tap = 2 * T + (kl >> 4);
      int ci = kl & 15;
      t[j] = (short)(tap < 9 ? f2bf(w[(tap * 16 + ci) * 32 + 2 * c + f]) : 0);
    }
    U4S8 u;
    u.s = t;
    tab[(conv * 10 + slot) * 64 + tid] = u.u;
  }
}

__global__ __launch_bounds__(64) void build_tab_k2(
    const float* __restrict__ w12, const float* __restrict__ w3,
    const float* __restrict__ sums1, const float* __restrict__ sums2,
    const float* __restrict__ g0, const float* __restrict__ b0,
    const float* __restrict__ g1, const float* __restrict__ b1,
    uint4* __restrict__ tab, int n) {
  __shared__ float stl[64];
  const int conv = blockIdx.x / 20, slot = blockIdx.x % 20;
  const float* w = conv ? w3 : w12;
  const float* sums = conv ? sums2 : sums1;
  const float* bn_g = conv ? g1 : g0;
  const float* bn_b = conv ? b1 : b0;
  const int lane = threadIdx.x;
  if (lane < 32) {
    float ssum = 0.f, qsum = 0.f;
#pragma unroll
    for (int bk = 0; bk < NBANK; bk++) {  // reduce spread banks
      ssum += sums[bk * 64 + lane];
      qsum += sums[bk * 64 + 32 + lane];
    }
    float inv_n = 1.0f / (float)n;
    float m = ssum * inv_n;
    float v = qsum * inv_n - m * m;
    float s = bn_g[lane] * rsqrtf(v + EPS);
    stl[lane] = s;
    stl[32 + lane] = bn_b[lane] - m * s;
  }
  __syncthreads();
  const int g = lane >> 4, c = lane & 15;
  s8v t;
  if (slot < 18) {
    const int k = slot >> 1, f = slot & 1;
#pragma unroll
    for (int j = 0; j < 8; j++) {
      int ci = g * 8 + j;
      t[j] = (short)f2bf(w[(k * 32 + ci) * 32 + 2 * c + f] * stl[ci]);
    }
  } else {
    const int f = slot - 18;
#pragma unroll
    for (int j = 0; j < 8; j++) {
      int kk = g * 8 + j;
      if (kk < 9) {
        float a = 0.f;
        for (int ci = 0; ci < 32; ci++)
          a += stl[32 + ci] * w[(kk * 32 + ci) * 32 + 2 * c + f];
        t[j] = (short)f2bf(a);
      } else {
        t[j] = 0;
      }
    }
  }
  U4S8 u;
  u.s = t;
  tab[(conv * 20 + slot) * 64 + lane] = u.u;
}

// ---------------------------------------------------------------------------
// Pipeline helpers (forceinline; array refs resolve to caller registers).
// ---------------------------------------------------------------------------
__device__ __forceinline__ void load_idx(const int* __restrict__ nbr, int n,
                                         int pt, int (&JJ)[9]) {
  bool a = pt < n;
#pragma unroll
  for (int k = 0; k < 9; k++) JJ[k] = a ? nbr[(size_t)k * n + pt] : -1;
}

// UNCONDITIONAL gathers (R18): dead slots read the maintained zero row n --
// all lanes of a c-group hit the SAME line (L1 broadcast, ~free). Static
// load schedule => compiler emits COUNTED vmcnt, so next-tile prefetch
// survives across this tile's MFMAs. Ballots computed after load issue.
template <bool PAIRED, int NS>
__device__ __forceinline__ void produce(const unsigned short* __restrict__ src,
                                        int n, int g, const int (&JJ)[9],
                                        uint4 (&GA)[NS], unsigned& VM,
                                        unsigned& SON) {
#pragma unroll
  for (int s = 0; s < NS; s++) {
    int jr;
    if (PAIRED) {
      int jA = JJ[2 * s];
      int jB = JJ[(2 * s + 1 < 9) ? 2 * s + 1 : 8];
      jr = (g & 2) ? jB : jA;
    } else {
      jr = JJ[s];
    }
    unsigned jc = jr < 0 ? (unsigned)n : (unsigned)jr;  // zero row
    GA[s] = ((const uint4*)src)[PAIRED ? ((size_t)jc * 2 + (g & 1))
                                       : ((size_t)jc * 4 + g)];
  }
  VM = 0;
#pragma unroll
  for (int k = 0; k < 9; k++) VM |= (JJ[k] >= 0 ? 1u : 0u) << k;
  SON = 0;
#pragma unroll
  for (int s = 0; s < NS; s++) {
    bool on;
    if (PAIRED) {
      int jA = JJ[2 * s];
      int jB = JJ[(2 * s + 1 < 9) ? 2 * s + 1 : 8];
      on = __ballot(jA >= 0 || jB >= 0) != 0ull;
    } else {
      on = __ballot(JJ[s] >= 0) != 0ull;
    }
    SON |= (on ? 1u : 0u) << s;
  }
}

// ---------------------------------------------------------------------------
// MFMA subm-conv, R18: 2-deep pipeline (idx +2 tiles, gathers +1 tile) with
// UNCONDITIONAL gather issue. R17's conditional (slot_on-branched) gather
// issue made the outstanding-load count indeterminate => compiler fell back
// to s_waitcnt vmcnt(0) at every consumption, draining the prefetch and
// serializing each tile on full memory latency (the R16 counter signature:
// MfmaUtil 2.6%, VALUBusy 9.4%, HBM 8.7%). Unconditional issue keeps the
// schedule static (counted vmcnt); MFMA-side slot skipping retained (branchy
// consumption doesn't break counting). Launch bounds back to verified
// (256,3) for both kernels.
// ---------------------------------------------------------------------------
template <bool PAIRED>
__global__ __launch_bounds__(256, 3) void conv_mfma(
    const unsigned short* __restrict__ src0, const int* __restrict__ nbr0,
    const uint4* __restrict__ tab0, unsigned short* __restrict__ dst0,
    float* __restrict__ osums0, const unsigned short* __restrict__ src1,
    const int* __restrict__ nbr1, const uint4* __restrict__ tab1,
    unsigned short* __restrict__ dst1, float* __restrict__ osums1, int n,
    int gb) {
  constexpr int NS = PAIRED ? 5 : 9;      // mfma slots per tile
  constexpr int NSLOT = PAIRED ? 10 : 20; // table slots
  __shared__ uint4 bwl[NSLOT * 64];
  __shared__ float redl[4 * 64];

  const int tid = threadIdx.x;
  const bool second = (int)blockIdx.x >= gb;
  const unsigned short* src = second ? src1 : src0;
  const int* nbr = second ? nbr1 : nbr0;
  const uint4* tab = second ? tab1 : tab0;
  unsigned short* dst = second ? dst1 : dst0;
  float* osums = second ? osums1 : osums0;

  // stage table global -> LDS (coalesced)
  for (int i = tid; i < NSLOT * 64; i += 256) bwl[i] = tab[i];
  __syncthreads();

  const int lane = tid & 63;
  const int wv = tid >> 6;
  const int g = lane >> 4;  // k-chunk group 0..3
  const int c = lane & 15;  // A row (point) / B col index (cout pair c)

  s8v bbias0, bbias1;
  if (!PAIRED) {
    U4S8 x;
    x.u = bwl[18 * 64 + lane];
    bbias0 = x.s;
    x.u = bwl[19 * 64 + lane];
    bbias1 = x.s;
  }

  const int bid = second ? (int)blockIdx.x - gb : (int)blockIdx.x;
  const int wbase = bid * (64 * TPW) + wv * (16 * TPW);

  float s0 = 0.f, s1 = 0.f, q0 = 0.f, q1 = 0.f;  // stats accumulators

  // ---- software pipeline state: idx 2 tiles ahead, gathers 1 tile ahead ----
  int jjb[2][9];
  uint4 gab[2][NS];
  unsigned vmb[2], sonb[2];

  load_idx(nbr, n, wbase + c, jjb[0]);        // tile 0 indices
  load_idx(nbr, n, wbase + 16 + c, jjb[1]);   // tile 1 indices
  produce<PAIRED, NS>(src, n, g, jjb[0], gab[0], vmb[0], sonb[0]);  // tile 0

#pragma unroll
  for (int t = 0; t < TPW; t++) {  // FULL unroll: static ping-pong indices
    const int cur = t & 1, nxt = 1 - (t & 1);
    const int pbase = wbase + t * 16;

    if (t + 1 < TPW)  // issue gathers for tile t+1 (indices from iter t-1)
      produce<PAIRED, NS>(src, n, g, jjb[nxt], gab[nxt], vmb[nxt], sonb[nxt]);
    if (t + 2 < TPW)  // issue indices for tile t+2 (into freed buffer)
      load_idx(nbr, n, pbase + 32 + c, jjb[cur]);
    __builtin_amdgcn_sched_barrier(0);  // pin: loads above, MFMAs below

    // ---- MFMA accumulate tile t (data gathered one tile ago) ----
    f4v acc0 = {0.f, 0.f, 0.f, 0.f};
    f4v acc1 = {0.f, 0.f, 0.f, 0.f};
#pragma unroll
    for (int s = 0; s < NS; s++) {
      if (sonb[cur] & (1u << s)) {  // wave-uniform scalar branch (MFMA skip)
        U4S8 a;
        a.u = gab[cur][s];
        U4S8 b0, b1;
        b0.u = bwl[(s * 2 + 0) * 64 + lane];
        b1.u = bwl[(s * 2 + 1) * 64 + lane];
        acc0 = __builtin_amdgcn_mfma_f32_16x16x32_bf16(a.s, b0.s, acc0, 0, 0, 0);
        acc1 = __builtin_amdgcn_mfma_f32_16x16x32_bf16(a.s, b1.s, acc1, 0, 0, 0);
      }
    }
    if (!PAIRED) {  // bias via validity-matrix MFMA (covers all taps)
      unsigned vmask = vmb[cur];
      s8v av;
#pragma unroll
      for (int j = 0; j < 8; j++) {
        unsigned kk = (unsigned)(g * 8 + j);
        unsigned bit = (kk < 32u) ? ((vmask >> kk) & 1u) : 0u;
        av[j] = (short)(bit ? 0x3F80 : 0);
      }
      acc0 = __builtin_amdgcn_mfma_f32_16x16x32_bf16(av, bbias0, acc0, 0, 0, 0);
      acc1 = __builtin_amdgcn_mfma_f32_16x16x32_bf16(av, bbias1, acc1, 0, 0, 0);
    }

    // ---- lrelu + stats ----
#pragma unroll
    for (int r = 0; r < 4; r++) {
      float x = acc0[r];
      x = fmaxf(x, SLOPE * x);
      acc0[r] = x;
      s0 += x;
      q0 = fmaf(x, x, q0);
      float y = acc1[r];
      y = fmaxf(y, SLOPE * y);
      acc1[r] = y;
      s1 += y;
      q1 = fmaf(y, y, q1);
    }

    // ---- direct coalesced store: lane (g,c) owns points pbase+g*4+r,
    //      couts (2c,2c+1) -> one packed bf16x2 dword each ----
#pragma unroll
    for (int r = 0; r < 4; r++) {
      int p = pbase + g * 4 + r;
      if (p < n)
        ((unsigned*)dst)[(size_t)p * 16 + c] =
            f2bf(acc0[r]) | (f2bf(acc1[r]) << 16);
    }
  }

  // ---- block stats reduction, one atomic per channel into spread bank ----
  s0 += __shfl_xor(s0, 16, 64);
  s0 += __shfl_xor(s0, 32, 64);
  s1 += __shfl_xor(s1, 16, 64);
  s1 += __shfl_xor(s1, 32, 64);
  q0 += __shfl_xor(q0, 16, 64);
  q0 += __shfl_xor(q0, 32, 64);
  q1 += __shfl_xor(q1, 16, 64);
  q1 += __shfl_xor(q1, 32, 64);
  if (lane < 16) {
    redl[wv * 64 + 2 * c] = s0;
    redl[wv * 64 + 2 * c + 1] = s1;
    redl[wv * 64 + 32 + 2 * c] = q0;
    redl[wv * 64 + 32 + 2 * c + 1] = q1;
  }
  __syncthreads();
  if (tid < 64) {
    float t = redl[tid] + redl[64 + tid] + redl[128 + tid] + redl[192 + tid];
    atomicAdd(&osums[(bid & (NBANK - 1)) * 64 + tid], t);
  }
}

// out = bnA(z12) + bnB(z3), both inputs bf16 [n][32]; sums are NBANK-spread
__global__ __launch_bounds__(256) void final_kernel(
    const uint4* __restrict__ z12, const uint4* __restrict__ z3,
    float* __restrict__ out, const float* __restrict__ sumsA,
    const float* __restrict__ gA, const float* __restrict__ bA,
    const float* __restrict__ sumsB, const float* __restrict__ gB,
    const float* __restrict__ bB, int n) {
  __shared__ float st[128];  // sA tA sB tB
  const int tid = threadIdx.x;
  if (tid < 32) {
    float sa = 0.f, qa = 0.f, sb = 0.f, qb = 0.f;
#pragma unroll
    for (int bk = 0; bk < NBANK; bk++) {
      sa += sumsA[bk * 64 + tid];
      qa += sumsA[bk * 64 + 32 + tid];
      sb += sumsB[bk * 64 + tid];
      qb += sumsB[bk * 64 + 32 + tid];
    }
    float inv_n = 1.0f / (float)n;
    float m = sa * inv_n;
    float v = qa * inv_n - m * m;
    float s = gA[tid] * rsqrtf(v + EPS);
    st[tid] = s;
    st[32 + tid] = bA[tid] - m * s;
    m = sb * inv_n;
    v = qb * inv_n - m * m;
    s = gB[tid] * rsqrtf(v + EPS);
    st[64 + tid] = s;
    st[96 + tid] = bB[tid] - m * s;
  }
  __syncthreads();
  const int total = n * 4;  // 8-channel chunks
  for (int i = blockIdx.x * 256 + tid; i < total; i += gridDim.x * 256) {
    int c0 = (i & 3) * 8;
    uint4 a = z12[i], b = z3[i];
    float4 r0, r1;
    r0.x = bf_lo(a.x) * st[c0 + 0] + st[32 + c0 + 0] + bf_lo(b.x) * st[64 + c0 + 0] + st[96 + c0 + 0];
    r0.y = bf_hi(a.x) * st[c0 + 1] + st[32 + c0 + 1] + bf_hi(b.x) * st[64 + c0 + 1] + st[96 + c0 + 1];
    r0.z = bf_lo(a.y) * st[c0 + 2] + st[32 + c0 + 2] + bf_lo(b.y) * st[64 + c0 + 2] + st[96 + c0 + 2];
    r0.w = bf_hi(a.y) * st[c0 + 3] + st[32 + c0 + 3] + bf_hi(b.y) * st[64 + c0 + 3] + st[96 + c0 + 3];
    r1.x = bf_lo(a.z) * st[c0 + 4] + st[32 + c0 + 4] + bf_lo(b.z) * st[64 + c0 + 4] + st[96 + c0 + 4];
    r1.y = bf_hi(a.z) * st[c0 + 5] + st[32 + c0 + 5] + bf_hi(b.z) * st[64 + c0 + 5] + st[96 + c0 + 5];
    r1.z = bf_lo(a.w) * st[c0 + 6] + st[32 + c0 + 6] + bf_lo(b.w) * st[64 + c0 + 6] + st[96 + c0 + 6];
    r1.w = bf_hi(a.w) * st[c0 + 7] + st[32 + c0 + 7] + bf_hi(b.w) * st[64 + c0 + 7] + st[96 + c0 + 7];
    ((float4*)out)[2 * i + 0] = r0;
    ((float4*)out)[2 * i + 1] = r1;
  }
}

extern "C" void kernel_launch(void* const* d_in, const int* in_sizes, int n_in,
                              void* d_out, int out_size, void* d_ws,
                              size_t ws_size, hipStream_t stream) {
  const float* features = (const float*)d_in[0];
  const int* nbr133 = (const int*)d_in[1];
  const int* nbr313 = (const int*)d_in[2];
  const float* conv1_w = (const float*)d_in[3];
  const float* conv12_w = (const float*)d_in[4];
  const float* conv2_w = (const float*)d_in[5];
  const float* conv3_w = (const float*)d_in[6];
  const float* bn0_g = (const float*)d_in[7];
  const float* bn0_b = (const float*)d_in[8];
  const float* bn02_g = (const float*)d_in[9];
  const float* bn02_b = (const float*)d_in[10];
  const float* bn1_g = (const float*)d_in[11];
  const float* bn1_b = (const float*)d_in[12];
  const float* bn2_g = (const float*)d_in[13];
  const float* bn2_b = (const float*)d_in[14];
  float* out = (float*)d_out;

  const int n = in_sizes[0] / 16;  // 250000
  char* ws = (char*)d_ws;
  const size_t A = (size_t)n * 64 + 64;  // bf16 [n+1][32] region

  // region0: fbf ([n+1][16] bf16) overlaid later by z12 ([n][32] bf16)
  unsigned short* fbf = (unsigned short*)ws;
  unsigned short* z12 = (unsigned short*)ws;
  unsigned short* zA1 = (unsigned short*)(ws + A);
  unsigned short* zA2 = (unsigned short*)(ws + 2 * A);
  unsigned short* z3 = (unsigned short*)(ws + 3 * A);
  float* sums = (float*)(ws + 4 * A);
  // sums: 4 stat sets x NBANK banks x 64 floats:
  //   +0 z1 | +1024 z2 | +2048 z12 | +3072 z3
  uint4* tabK1 = (uint4*)(ws + 4 * A + 4 * NBANK * 64 * 4);
  uint4* tabK2 = tabK1 + 20 * 64;

  const int n8 = n * 2;  // 8-float chunks of features
  const int nc = (n8 + 255) / 256;
  // fused prep: cvt | init | tabK1 build
  prep_kernel<<<nc + 21, 256, 0, stream>>>(
      features, (uint4*)fbf, n8, conv1_w, conv2_w, tabK1, sums,
      (uint4*)(ws + (size_t)n * 32),            // fbf row n
      (uint4*)(ws + A + (size_t)n * 64),        // zA1 row n
      (uint4*)(ws + 2 * A + (size_t)n * 64),    // zA2 row n
      nc);

  const int gb = (n + 64 * TPW - 1) / (64 * TPW);
  // K1: conv1 (fbf,nbr133)->zA1 || conv2 (fbf,nbr313)->zA2
  conv_mfma<true><<<2 * gb, 256, 0, stream>>>(
      fbf, nbr133, tabK1, zA1, sums + 0, fbf, nbr313, tabK1 + 10 * 64, zA2,
      sums + 1024, n, gb);
  // tables for K2 (BN of K1 folded in; needs K1 stats)
  build_tab_k2<<<40, 64, 0, stream>>>(conv12_w, conv3_w, sums + 0, sums + 1024,
                                      bn0_g, bn0_b, bn1_g, bn1_b, tabK2, n);
  // K2: conv12 (bn0(zA1),nbr313)->z12 || conv3 (bn1(zA2),nbr133)->z3
  conv_mfma<false><<<2 * gb, 256, 0, stream>>>(
      zA1, nbr313, tabK2, z12, sums + 2048, zA2, nbr133, tabK2 + 20 * 64, z3,
      sums + 3072, n, gb);
  // out = bn02(z12) + bn2(z3)
  final_kernel<<<1024, 256, 0, stream>>>((const uint4*)z12, (const uint4*)z3,
                                         out, sums + 2048, bn02_g, bn02_b,
                                         sums + 3072, bn2_g, bn2_b, n);
}

// Round 6
// 71.551 us; speedup vs baseline: 1.8851x; 1.0522x over previous
//
#include <hip/hip_runtime.h>

#define EPS 1e-3f
#define SLOPE 0.01f
#define TPW 4   // 16-point tiles per wave
#define NBANK 16  // stats atomic spread banks

typedef __attribute__((ext_vector_type(8))) short s8v;
typedef __attribute__((ext_vector_type(4))) float f4v;

union U4S8 {
  uint4 u;
  s8v s;
};

static __device__ inline unsigned f2bf(float x) {  // RNE f32->bf16 (low 16)
  unsigned u = __float_as_uint(x);
  return (u + 0x7fffu + ((u >> 16) & 1u)) >> 16;
}
static __device__ inline float bf_lo(unsigned u) {
  return __uint_as_float(u << 16);
}
static __device__ inline float bf_hi(unsigned u) {
  return __uint_as_float(u & 0xffff0000u);
}

// ---------------------------------------------------------------------------
// prep kernel: fused {feature f32->bf16 convert | sums/zero-row init |
// K1 B-fragment table build}. One dispatch replaces three tiny ones.
// ---------------------------------------------------------------------------
__global__ __launch_bounds__(256) void prep_kernel(
    const float* __restrict__ features, uint4* __restrict__ fbf, int n8,
    const float* __restrict__ w1, const float* __restrict__ w2,
    uint4* __restrict__ tab, float* __restrict__ sums, uint4* __restrict__ r0,
    uint4* __restrict__ r1, uint4* __restrict__ r2, int nc) {
  const int b = blockIdx.x;
  const int tid = threadIdx.x;
  if (b < nc) {  // cvt: features f32 -> bf16 rows
    int i = b * 256 + tid;
    if (i < n8) {
      const float4* p = (const float4*)features + (size_t)i * 2;
      float4 a = p[0], bb = p[1];
      uint4 o;
      o.x = f2bf(a.x) | (f2bf(a.y) << 16);
      o.y = f2bf(a.z) | (f2bf(a.w) << 16);
      o.z = f2bf(bb.x) | (f2bf(bb.y) << 16);
      o.w = f2bf(bb.z) | (f2bf(bb.w) << 16);
      fbf[i] = o;
    }
  } else if (b == nc) {  // init: stats accumulators + zero rows
#pragma unroll
    for (int i = 0; i < 16; i++) sums[i * 256 + tid] = 0.f;
    uint4 z = {0u, 0u, 0u, 0u};
    if (tid < 2) r0[tid] = z;
    else if (tid < 6) r1[tid - 2] = z;
    else if (tid < 10) r2[tid - 6] = z;
  } else if (tid < 64) {  // build K1 tables (20 slot-blocks)
    const int sb = b - nc - 1;  // 0..19
    const int conv = sb / 10, slot = sb % 10;
    const float* w = conv ? w2 : w1;
    const int T = slot >> 1, f = slot & 1;
    const int g = tid >> 4, c = tid & 15;
    s8v t;
#pragma unroll
    for (int j = 0; j < 8; j++) {
      int kl = g * 8 + j;
      int tap = 2 * T + (kl >> 4);
      int ci = kl & 15;
      t[j] = (short)(tap < 9 ? f2bf(w[(tap * 16 + ci) * 32 + 2 * c + f]) : 0);
    }
    U4S8 u;
    u.s = t;
    tab[(conv * 10 + slot) * 64 + tid] = u.u;
  }
}

__global__ __launch_bounds__(64) void build_tab_k2(
    const float* __restrict__ w12, const float* __restrict__ w3,
    const float* __restrict__ sums1, const float* __restrict__ sums2,
    const float* __restrict__ g0, const float* __restrict__ b0,
    const float* __restrict__ g1, const float* __restrict__ b1,
    uint4* __restrict__ tab, int n) {
  __shared__ float stl[64];
  const int conv = blockIdx.x / 20, slot = blockIdx.x % 20;
  const float* w = conv ? w3 : w12;
  const float* sums = conv ? sums2 : sums1;
  const float* bn_g = conv ? g1 : g0;
  const float* bn_b = conv ? b1 : b0;
  const int lane = threadIdx.x;
  if (lane < 32) {
    float ssum = 0.f, qsum = 0.f;
#pragma unroll
    for (int bk = 0; bk < NBANK; bk++) {  // reduce spread banks
      ssum += sums[bk * 64 + lane];
      qsum += sums[bk * 64 + 32 + lane];
    }
    float inv_n = 1.0f / (float)n;
    float m = ssum * inv_n;
    float v = qsum * inv_n - m * m;
    float s = bn_g[lane] * rsqrtf(v + EPS);
    stl[lane] = s;
    stl[32 + lane] = bn_b[lane] - m * s;
  }
  __syncthreads();
  const int g = lane >> 4, c = lane & 15;
  s8v t;
  if (slot < 18) {
    const int k = slot >> 1, f = slot & 1;
#pragma unroll
    for (int j = 0; j < 8; j++) {
      int ci = g * 8 + j;
      t[j] = (short)f2bf(w[(k * 32 + ci) * 32 + 2 * c + f] * stl[ci]);
    }
  } else {
    const int f = slot - 18;
#pragma unroll
    for (int j = 0; j < 8; j++) {
      int kk = g * 8 + j;
      if (kk < 9) {
        float a = 0.f;
        for (int ci = 0; ci < 32; ci++)
          a += stl[32 + ci] * w[(kk * 32 + ci) * 32 + 2 * c + f];
        t[j] = (short)f2bf(a);
      } else {
        t[j] = 0;
      }
    }
  }
  U4S8 u;
  u.s = t;
  tab[(conv * 20 + slot) * 64 + lane] = u.u;
}

// ---------------------------------------------------------------------------
// MFMA subm-conv, R19: OCCUPANCY experiment. R17/R18 proved within-wave
// pipelining is not the lever (both within noise of unpipelined R12); the
// surviving theory is TLP: R16's direct measurement showed the conv
// structure at 8 waves/CU is pure-latency-bound (MfmaUtil 2.6%, VALU 9.4%,
// HBM 8.7%), and baseline runs only 12 waves/CU. This round: 4 blocks/CU
// (launch_bounds(256,4), 16 waves/CU, +33% TLP), with register state cut to
// fit the 128-VGPR cap without spills: no next-tile index prefetch, no
// ping-pong buffers -- per tile: idx load -> UNCONDITIONAL gathers (dead
// slots read maintained zero row n; keeps the load schedule static for
// counted vmcnt) -> slot-skipped MFMAs. Est VGPR ~100-115 < 128.
// LDS: K2 21.5KB x4 = 86KB, K1 11.25KB x4 = 45KB (both fit).
// ---------------------------------------------------------------------------
template <bool PAIRED>
__global__ __launch_bounds__(256, 4) void conv_mfma(
    const unsigned short* __restrict__ src0, const int* __restrict__ nbr0,
    const uint4* __restrict__ tab0, unsigned short* __restrict__ dst0,
    float* __restrict__ osums0, const unsigned short* __restrict__ src1,
    const int* __restrict__ nbr1, const uint4* __restrict__ tab1,
    unsigned short* __restrict__ dst1, float* __restrict__ osums1, int n,
    int gb) {
  constexpr int NS = PAIRED ? 5 : 9;      // mfma slots per tile
  constexpr int NSLOT = PAIRED ? 10 : 20; // table slots
  __shared__ uint4 bwl[NSLOT * 64];
  __shared__ float redl[4 * 64];

  const int tid = threadIdx.x;
  const bool second = (int)blockIdx.x >= gb;
  const unsigned short* src = second ? src1 : src0;
  const int* nbr = second ? nbr1 : nbr0;
  const uint4* tab = second ? tab1 : tab0;
  unsigned short* dst = second ? dst1 : dst0;
  float* osums = second ? osums1 : osums0;

  // stage table global -> LDS (coalesced)
  for (int i = tid; i < NSLOT * 64; i += 256) bwl[i] = tab[i];
  __syncthreads();

  const int lane = tid & 63;
  const int wv = tid >> 6;
  const int g = lane >> 4;  // k-chunk group 0..3
  const int c = lane & 15;  // A row (point) / B col index (cout pair c)

  s8v bbias0, bbias1;
  if (!PAIRED) {
    U4S8 x;
    x.u = bwl[18 * 64 + lane];
    bbias0 = x.s;
    x.u = bwl[19 * 64 + lane];
    bbias1 = x.s;
  }

  const int bid = second ? (int)blockIdx.x - gb : (int)blockIdx.x;
  const int wbase = bid * (64 * TPW) + wv * (16 * TPW);

  float s0 = 0.f, s1 = 0.f, q0 = 0.f, q1 = 0.f;  // stats accumulators

#pragma unroll 1
  for (int t = 0; t < TPW; t++) {
    const int pbase = wbase + t * 16;

    // ---- tile indices (coalesced; per-lane point pbase+c) ----
    int jj[9];
    {
      int pt = pbase + c;
      bool a = pt < n;
#pragma unroll
      for (int k = 0; k < 9; k++) jj[k] = a ? nbr[(size_t)k * n + pt] : -1;
    }

    // ---- UNCONDITIONAL gathers (dead lanes read zero row n: L1-hot line,
    //      broadcast within c-group; static schedule => counted vmcnt) ----
    uint4 ga[NS];
#pragma unroll
    for (int s = 0; s < NS; s++) {
      int jr;
      if (PAIRED) {
        int jA = jj[2 * s];
        int jB = jj[(2 * s + 1 < 9) ? 2 * s + 1 : 8];
        jr = (g & 2) ? jB : jA;
      } else {
        jr = jj[s];
      }
      unsigned jc = jr < 0 ? (unsigned)n : (unsigned)jr;  // zero row
      ga[s] = ((const uint4*)src)[PAIRED ? ((size_t)jc * 2 + (g & 1))
                                         : ((size_t)jc * 4 + g)];
    }

    // ---- per-slot wave-uniform validity (ballot -> scalar MFMA skip) ----
    unsigned vmask = 0;
    if (!PAIRED) {
#pragma unroll
      for (int k = 0; k < 9; k++) vmask |= (jj[k] >= 0 ? 1u : 0u) << k;
    }
    unsigned son = 0;
#pragma unroll
    for (int s = 0; s < NS; s++) {
      bool on;
      if (PAIRED) {
        int jA = jj[2 * s];
        int jB = jj[(2 * s + 1 < 9) ? 2 * s + 1 : 8];
        on = __ballot(jA >= 0 || jB >= 0) != 0ull;
      } else {
        on = __ballot(jj[s] >= 0) != 0ull;
      }
      son |= (on ? 1u : 0u) << s;
    }

    // ---- MFMA accumulate (live slots only) ----
    f4v acc0 = {0.f, 0.f, 0.f, 0.f};
    f4v acc1 = {0.f, 0.f, 0.f, 0.f};
#pragma unroll
    for (int s = 0; s < NS; s++) {
      if (son & (1u << s)) {  // wave-uniform scalar branch
        U4S8 a;
        a.u = ga[s];
        U4S8 b0, b1;
        b0.u = bwl[(s * 2 + 0) * 64 + lane];
        b1.u = bwl[(s * 2 + 1) * 64 + lane];
        acc0 = __builtin_amdgcn_mfma_f32_16x16x32_bf16(a.s, b0.s, acc0, 0, 0, 0);
        acc1 = __builtin_amdgcn_mfma_f32_16x16x32_bf16(a.s, b1.s, acc1, 0, 0, 0);
      }
    }
    if (!PAIRED) {  // bias via validity-matrix MFMA (covers all taps)
      s8v av;
#pragma unroll
      for (int j = 0; j < 8; j++) {
        unsigned kk = (unsigned)(g * 8 + j);
        unsigned bit = (kk < 32u) ? ((vmask >> kk) & 1u) : 0u;
        av[j] = (short)(bit ? 0x3F80 : 0);
      }
      acc0 = __builtin_amdgcn_mfma_f32_16x16x32_bf16(av, bbias0, acc0, 0, 0, 0);
      acc1 = __builtin_amdgcn_mfma_f32_16x16x32_bf16(av, bbias1, acc1, 0, 0, 0);
    }

    // ---- lrelu + stats ----
#pragma unroll
    for (int r = 0; r < 4; r++) {
      float x = acc0[r];
      x = fmaxf(x, SLOPE * x);
      acc0[r] = x;
      s0 += x;
      q0 = fmaf(x, x, q0);
      float y = acc1[r];
      y = fmaxf(y, SLOPE * y);
      acc1[r] = y;
      s1 += y;
      q1 = fmaf(y, y, q1);
    }

    // ---- direct coalesced store: lane (g,c) owns points pbase+g*4+r,
    //      couts (2c,2c+1) -> one packed bf16x2 dword each ----
#pragma unroll
    for (int r = 0; r < 4; r++) {
      int p = pbase + g * 4 + r;
      if (p < n)
        ((unsigned*)dst)[(size_t)p * 16 + c] =
            f2bf(acc0[r]) | (f2bf(acc1[r]) << 16);
    }
  }

  // ---- block stats reduction, one atomic per channel into spread bank ----
  s0 += __shfl_xor(s0, 16, 64);
  s0 += __shfl_xor(s0, 32, 64);
  s1 += __shfl_xor(s1, 16, 64);
  s1 += __shfl_xor(s1, 32, 64);
  q0 += __shfl_xor(q0, 16, 64);
  q0 += __shfl_xor(q0, 32, 64);
  q1 += __shfl_xor(q1, 16, 64);
  q1 += __shfl_xor(q1, 32, 64);
  if (lane < 16) {
    redl[wv * 64 + 2 * c] = s0;
    redl[wv * 64 + 2 * c + 1] = s1;
    redl[wv * 64 + 32 + 2 * c] = q0;
    redl[wv * 64 + 32 + 2 * c + 1] = q1;
  }
  __syncthreads();
  if (tid < 64) {
    float t = redl[tid] + redl[64 + tid] + redl[128 + tid] + redl[192 + tid];
    atomicAdd(&osums[(bid & (NBANK - 1)) * 64 + tid], t);
  }
}

// out = bnA(z12) + bnB(z3), both inputs bf16 [n][32]; sums are NBANK-spread
__global__ __launch_bounds__(256) void final_kernel(
    const uint4* __restrict__ z12, const uint4* __restrict__ z3,
    float* __restrict__ out, const float* __restrict__ sumsA,
    const float* __restrict__ gA, const float* __restrict__ bA,
    const float* __restrict__ sumsB, const float* __restrict__ gB,
    const float* __restrict__ bB, int n) {
  __shared__ float st[128];  // sA tA sB tB
  const int tid = threadIdx.x;
  if (tid < 32) {
    float sa = 0.f, qa = 0.f, sb = 0.f, qb = 0.f;
#pragma unroll
    for (int bk = 0; bk < NBANK; bk++) {
      sa += sumsA[bk * 64 + tid];
      qa += sumsA[bk * 64 + 32 + tid];
      sb += sumsB[bk * 64 + tid];
      qb += sumsB[bk * 64 + 32 + tid];
    }
    float inv_n = 1.0f / (float)n;
    float m = sa * inv_n;
    float v = qa * inv_n - m * m;
    float s = gA[tid] * rsqrtf(v + EPS);
    st[tid] = s;
    st[32 + tid] = bA[tid] - m * s;
    m = sb * inv_n;
    v = qb * inv_n - m * m;
    s = gB[tid] * rsqrtf(v + EPS);
    st[64 + tid] = s;
    st[96 + tid] = bB[tid] - m * s;
  }
  __syncthreads();
  const int total = n * 4;  // 8-channel chunks
  for (int i = blockIdx.x * 256 + tid; i < total; i += gridDim.x * 256) {
    int c0 = (i & 3) * 8;
    uint4 a = z12[i], b = z3[i];
    float4 r0, r1;
    r0.x = bf_lo(a.x) * st[c0 + 0] + st[32 + c0 + 0] + bf_lo(b.x) * st[64 + c0 + 0] + st[96 + c0 + 0];
    r0.y = bf_hi(a.x) * st[c0 + 1] + st[32 + c0 + 1] + bf_hi(b.x) * st[64 + c0 + 1] + st[96 + c0 + 1];
    r0.z = bf_lo(a.y) * st[c0 + 2] + st[32 + c0 + 2] + bf_lo(b.y) * st[64 + c0 + 2] + st[96 + c0 + 2];
    r0.w = bf_hi(a.y) * st[c0 + 3] + st[32 + c0 + 3] + bf_hi(b.y) * st[64 + c0 + 3] + st[96 + c0 + 3];
    r1.x = bf_lo(a.z) * st[c0 + 4] + st[32 + c0 + 4] + bf_lo(b.z) * st[64 + c0 + 4] + st[96 + c0 + 4];
    r1.y = bf_hi(a.z) * st[c0 + 5] + st[32 + c0 + 5] + bf_hi(b.z) * st[64 + c0 + 5] + st[96 + c0 + 5];
    r1.z = bf_lo(a.w) * st[c0 + 6] + st[32 + c0 + 6] + bf_lo(b.w) * st[64 + c0 + 6] + st[96 + c0 + 6];
    r1.w = bf_hi(a.w) * st[c0 + 7] + st[32 + c0 + 7] + bf_hi(b.w) * st[64 + c0 + 7] + st[96 + c0 + 7];
    ((float4*)out)[2 * i + 0] = r0;
    ((float4*)out)[2 * i + 1] = r1;
  }
}

extern "C" void kernel_launch(void* const* d_in, const int* in_sizes, int n_in,
                              void* d_out, int out_size, void* d_ws,
                              size_t ws_size, hipStream_t stream) {
  const float* features = (const float*)d_in[0];
  const int* nbr133 = (const int*)d_in[1];
  const int* nbr313 = (const int*)d_in[2];
  const float* conv1_w = (const float*)d_in[3];
  const float* conv12_w = (const float*)d_in[4];
  const float* conv2_w = (const float*)d_in[5];
  const float* conv3_w = (const float*)d_in[6];
  const float* bn0_g = (const float*)d_in[7];
  const float* bn0_b = (const float*)d_in[8];
  const float* bn02_g = (const float*)d_in[9];
  const float* bn02_b = (const float*)d_in[10];
  const float* bn1_g = (const float*)d_in[11];
  const float* bn1_b = (const float*)d_in[12];
  const float* bn2_g = (const float*)d_in[13];
  const float* bn2_b = (const float*)d_in[14];
  float* out = (float*)d_out;

  const int n = in_sizes[0] / 16;  // 250000
  char* ws = (char*)d_ws;
  const size_t A = (size_t)n * 64 + 64;  // bf16 [n+1][32] region

  // region0: fbf ([n+1][16] bf16) overlaid later by z12 ([n][32] bf16)
  unsigned short* fbf = (unsigned short*)ws;
  unsigned short* z12 = (unsigned short*)ws;
  unsigned short* zA1 = (unsigned short*)(ws + A);
  unsigned short* zA2 = (unsigned short*)(ws + 2 * A);
  unsigned short* z3 = (unsigned short*)(ws + 3 * A);
  float* sums = (float*)(ws + 4 * A);
  // sums: 4 stat sets x NBANK banks x 64 floats:
  //   +0 z1 | +1024 z2 | +2048 z12 | +3072 z3
  uint4* tabK1 = (uint4*)(ws + 4 * A + 4 * NBANK * 64 * 4);
  uint4* tabK2 = tabK1 + 20 * 64;

  const int n8 = n * 2;  // 8-float chunks of features
  const int nc = (n8 + 255) / 256;
  // fused prep: cvt | init | tabK1 build
  prep_kernel<<<nc + 21, 256, 0, stream>>>(
      features, (uint4*)fbf, n8, conv1_w, conv2_w, tabK1, sums,
      (uint4*)(ws + (size_t)n * 32),            // fbf row n
      (uint4*)(ws + A + (size_t)n * 64),        // zA1 row n
      (uint4*)(ws + 2 * A + (size_t)n * 64),    // zA2 row n
      nc);

  const int gb = (n + 64 * TPW - 1) / (64 * TPW);
  // K1: conv1 (fbf,nbr133)->zA1 || conv2 (fbf,nbr313)->zA2
  conv_mfma<true><<<2 * gb, 256, 0, stream>>>(
      fbf, nbr133, tabK1, zA1, sums + 0, fbf, nbr313, tabK1 + 10 * 64, zA2,
      sums + 1024, n, gb);
  // tables for K2 (BN of K1 folded in; needs K1 stats)
  build_tab_k2<<<40, 64, 0, stream>>>(conv12_w, conv3_w, sums + 0, sums + 1024,
                                      bn0_g, bn0_b, bn1_g, bn1_b, tabK2, n);
  // K2: conv12 (bn0(zA1),nbr313)->z12 || conv3 (bn1(zA2),nbr133)->z3
  conv_mfma<false><<<2 * gb, 256, 0, stream>>>(
      zA1, nbr313, tabK2, z12, sums + 2048, zA2, nbr133, tabK2 + 20 * 64, z3,
      sums + 3072, n, gb);
  // out = bn02(z12) + bn2(z3)
  final_kernel<<<1024, 256, 0, stream>>>((const uint4*)z12, (const uint4*)z3,
                                         out, sums + 2048, bn02_g, bn02_b,
                                         sums + 3072, bn2_g, bn2_b, n);
}